// Round 21
// baseline (2235.592 us; speedup 1.0000x reference)
//
#include <hip/hip_runtime.h>
#include <hip/hip_fp16.h>
#include <stdint.h>

typedef _Float16 f16;
typedef _Float16 f16x8 __attribute__((ext_vector_type(8)));
typedef _Float16 f16x4 __attribute__((ext_vector_type(4)));
typedef float f32x4 __attribute__((ext_vector_type(4)));
typedef unsigned u32x4 __attribute__((ext_vector_type(4)));

#define TSTEPS 512
#define NB 256        // 2 layers x 64 colgroups x 2 rowgroups
#define NT 512        // 8 waves
#define HN (32 * 1024)

__device__ __forceinline__ float sigm(float v) { return 1.0f / (1.0f + __expf(-v)); }

// sc0 sc1 = device-coherent (write-through to memory-side L3 / L3-read).
__device__ __forceinline__ void ld_coh(f16x8& d, const f16* p) {
  asm volatile("global_load_dwordx4 %0, %1, off sc0 sc1" : "=v"(d) : "v"(p));
}
__device__ __forceinline__ void ld_plain(f16x8& d, const f16* p) {
  asm volatile("global_load_dwordx4 %0, %1, off" : "=v"(d) : "v"(p));
}
__device__ __forceinline__ void st_coh_f16x8(f16* p, f16x8 v) {
  asm volatile("global_store_dwordx4 %0, %1, off sc0 sc1" :: "v"(p), "v"(v) : "memory");
}
__device__ __forceinline__ void st_coh_u32(unsigned* p, unsigned v) {
  asm volatile("global_store_dword %0, %1, off sc0 sc1" :: "v"(p), "v"(v) : "memory");
}
__device__ __forceinline__ u32x4 ld_coh_u4(const unsigned* p) {
  u32x4 d;
  asm volatile("global_load_dwordx4 %0, %1, off sc0 sc1" : "=v"(d) : "v"(p));
  return d;
}
__device__ __forceinline__ unsigned ld_coh_u32(const unsigned* p) {
  unsigned d;
  asm volatile("global_load_dword %0, %1, off sc0 sc1" : "=v"(d) : "v"(p));
  return d;
}

// R20 core (row-split, registers weights, coalesced h exchange via LDS bounce,
// pipelined vmcnt drain, vectorized reduce, slim barriers) + chain cuts:
//  (1) gate duty moved to WAVE 1 (w0 is busy with h-store drain + flag post;
//      w1 is free after barrier [C]) -> store-drain overlaps gate machinery.
//  (2) gen replicated x64 at 64B stride: bid0-w1's 64 lanes post all copies
//      with one store; block bid polls copy (bid&63) -> <=4 pollers per line
//      instead of 255 on one line. Same single-release-point semantics as all
//      green rounds (R2/R7/R8/R15/R19/R20) -- only the fan-out medium widens.
// Protocol otherwise byte-identical: store-drain -> flag[bid] -> bid0 scans
// 256 flags -> gen -> all gate on gen>=s. Rule #18 on every poll.
template<int USE_X16>
__global__ __launch_bounds__(NT, 2)
void sublstm_persistent(const float* __restrict__ x,
                        const float* __restrict__ wih0, const float* __restrict__ whh0,
                        const float* __restrict__ b0,
                        const float* __restrict__ wih1, const float* __restrict__ whh1,
                        const float* __restrict__ b1,
                        const f16* __restrict__ x16,
                        f16* __restrict__ h1buf, f16* __restrict__ h2buf,
                        unsigned* __restrict__ bar,   // [0..255] flags, [1024+j*16] gen copies
                        float* __restrict__ out)
{
  __shared__ float red[8][16][68];   // 34.8KB per-wave partials
  __shared__ float gatesS[16][68];   //  4.4KB
  __shared__ float biasS[64];
  __shared__ f16 stage[8][4096];     // 64KB: per-wave private h-slice stage
  __shared__ f16 hstageS[16][16];    // 512B: h-output gather tile

  const int bid   = blockIdx.x;
  const int layer = bid >> 7;
  const int n     = (bid & 127) >> 1;   // colgroup 0..63
  const int r     = bid & 1;            // rowgroup 0..1
  const int tid   = threadIdx.x;
  const int lane  = tid & 63;
  const int w     = tid >> 6;
  const int c15   = lane & 15;
  const int g4    = lane >> 4;
  const int l5    = lane & 31;
  const int lh    = lane >> 5;

  const float* wih = layer ? wih1 : wih0;
  const float* whh = layer ? whh1 : whh0;
  const float* bb  = layer ? b1   : b0;

  // one-time: 64-col weight slice -> registers (fp32 -> fp16), K-octant per wave
  const int kbase = w * 256 + g4 * 8;
  f16x8 breg[4][8];
  #pragma unroll
  for (int cc = 0; cc < 4; ++cc) {
    const int gate = cc * 1024 + (n << 4) + c15;
    const float* wr = (w < 4) ? (wih + (size_t)gate * 1024 + kbase)
                              : (whh + (size_t)gate * 1024 + (kbase - 1024));
    #pragma unroll
    for (int ks = 0; ks < 8; ++ks) {
      const float4 v0 = *(const float4*)(wr + ks * 32);
      const float4 v1 = *(const float4*)(wr + ks * 32 + 4);
      breg[cc][ks] = (f16x8){(f16)v0.x,(f16)v0.y,(f16)v0.z,(f16)v0.w,
                             (f16)v1.x,(f16)v1.y,(f16)v1.z,(f16)v1.w};
    }
  }
  if (tid < 64) biasS[tid] = bb[(tid >> 4) * 1024 + (n << 4) + (tid & 15)];
  __syncthreads();

  float c = 0.0f;        // cell state: thread tid<256 owns (lb = tid>>4, u = tid&15)
  f16x8 af[8];
  const int arow = r * 16 + c15;   // batch row for x frag loads

  for (int s = 0; s <= TSTEPS; ++s) {
    const int p_in  = s & 1;
    const int p_out = (s + 1) & 1;
    const bool active = (layer == 0) ? (s < TSTEPS) : (s >= 1);
    const int t = (layer == 0) ? s : (s - 1);
    const unsigned us = (unsigned)s;

    // x-issue early (plain cached; fire-and-forget before the gate)
    if (active && layer == 0 && w < 4) {
      if (USE_X16) {
        const f16* bp = x16 + ((size_t)t * 32 + arow) * 1024 + kbase;
        #pragma unroll
        for (int ks = 0; ks < 8; ++ks) ld_plain(af[ks], bp + ks * 32);
      } else {
        const float* bp = x + ((size_t)t * 32 + arow) * 1024 + kbase;
        #pragma unroll
        for (int ks = 0; ks < 8; ++ks) {
          const float4 v0 = *(const float4*)(bp + ks * 32);
          const float4 v1 = *(const float4*)(bp + ks * 32 + 4);
          af[ks] = (f16x8){(f16)v0.x,(f16)v0.y,(f16)v0.z,(f16)v0.w,
                           (f16)v1.x,(f16)v1.y,(f16)v1.z,(f16)v1.w};
        }
      }
    }

    // centralized gate on WAVE 1 (w0 is draining h-stores concurrently)  [A]
    if (s >= 1) {
      if (bid == 0) {
        if (w == 1) {
          while (true) {
            u32x4 d = ld_coh_u4(bar + (lane << 2));
            asm volatile("s_waitcnt vmcnt(0)" ::: "memory");
            __builtin_amdgcn_sched_barrier(0);
            if (__all(d.x >= us && d.y >= us && d.z >= us && d.w >= us)) break;
            __builtin_amdgcn_s_sleep(1);
          }
          st_coh_u32(bar + 1024 + lane * 16, us);   // 64 gen copies, one store
        }
      } else if (tid == 64) {                        // wave 1, lane 0
        const unsigned* gp = bar + 1024 + (bid & 63) * 16;
        while (true) {
          const unsigned gv = ld_coh_u32(gp);
          asm volatile("s_waitcnt vmcnt(0)" ::: "memory");
          __builtin_amdgcn_sched_barrier(0);
          if (gv >= us) break;
          __builtin_amdgcn_s_sleep(1);
        }
      }
      __syncthreads();
    }

    if (active) {
      if (!(layer == 0 && w < 4)) {
        // ---- coalesced h-slice load: 8 x 1KB contiguous instructions ----
        const f16* src; int kslice;
        if (layer == 0)   { src = h1buf + (size_t)p_in * HN; kslice = w * 256 - 1024; }
        else if (w < 4)   { src = h1buf + (size_t)p_in * HN; kslice = w * 256; }
        else              { src = h2buf + (size_t)p_in * HN; kslice = w * 256 - 1024; }
        #pragma unroll
        for (int i = 0; i < 8; ++i) {
          const int row = 2 * i + lh;                       // lanes 0-31: row 2i, 32-63: 2i+1
          ld_coh(af[i], src + (size_t)(r * 16 + row) * 1024 + kslice + l5 * 8);
        }
        // ---- pipelined stage: write each load as it retires (in-order) ----
        char* st = (char*)&stage[w][0];
#define DRAIN_WRITE(i, N)                                                        \
        asm volatile("s_waitcnt vmcnt(" N ")" ::: "memory");                     \
        { const int row_ = 2 * (i) + lh;                                         \
          const unsigned byte_ = ((unsigned)row_ << 9) |                         \
              ((((unsigned)l5 ^ ((unsigned)row_ & 7u)) << 4));                   \
          *(f16x8*)(st + byte_) = af[i]; }
        DRAIN_WRITE(0, "7")
        DRAIN_WRITE(1, "6")
        DRAIN_WRITE(2, "5")
        DRAIN_WRITE(3, "4")
        DRAIN_WRITE(4, "3")
        DRAIN_WRITE(5, "2")
        DRAIN_WRITE(6, "1")
        DRAIN_WRITE(7, "0")
#undef DRAIN_WRITE
        asm volatile("s_waitcnt lgkmcnt(0)" ::: "memory");
        __builtin_amdgcn_sched_barrier(0);
        // ---- fragment read from LDS (wave-private stage) ----
        #pragma unroll
        for (int ks = 0; ks < 8; ++ks) {
          const unsigned chunk = ((unsigned)(4 * ks + g4)) ^ ((unsigned)c15 & 7u);
          const unsigned byte = ((unsigned)c15 << 9) | (chunk << 4);
          af[ks] = *(const f16x8*)(st + byte);
        }
      }
      asm volatile("s_waitcnt vmcnt(0)" ::: "memory");
      __builtin_amdgcn_sched_barrier(0);

      f32x4 acc[4] = {{0,0,0,0},{0,0,0,0},{0,0,0,0},{0,0,0,0}};
      #pragma unroll
      for (int ks = 0; ks < 8; ++ks)
        #pragma unroll
        for (int cc = 0; cc < 4; ++cc)
          acc[cc] = __builtin_amdgcn_mfma_f32_16x16x32_f16(af[ks], breg[cc][ks], acc[cc], 0, 0, 0);

      // C frag: local row = g4*4 + rr, col = cc*16 + c15
      #pragma unroll
      for (int cc = 0; cc < 4; ++cc)
        #pragma unroll
        for (int rr = 0; rr < 4; ++rr)
          red[w][g4 * 4 + rr][cc * 16 + c15] = acc[cc][rr];
    }
    __syncthreads();   // [B] red complete across waves

    if (active && tid < 256) {
      // vectorized reduce: thread (lb, c4) sums 8 octant partials for 4 cols.
      const int lb = tid >> 4;
      const int c4 = (tid & 15) << 2;
      f32x4 tot = *(const f32x4*)&biasS[c4];
      #pragma unroll
      for (int ww = 0; ww < 8; ++ww) tot += *(const f32x4*)&red[ww][lb][c4];
      f32x4 sg;
      #pragma unroll
      for (int j = 0; j < 4; ++j) sg[j] = sigm(tot[j]);
      *(f32x4*)&gatesS[lb][c4] = sg;
    }
    // no barrier: cell reader's 4 source cols written by its own 16-thread
    // group (same wave); fence LDS program order only.
    asm volatile("s_waitcnt lgkmcnt(0)" ::: "memory");

    if (active && tid < 256) {
      const int lb = tid >> 4, u = tid & 15;
      const float ig = gatesS[lb][u];
      const float og = gatesS[lb][16 + u];
      const float zg = gatesS[lb][32 + u];
      const float fg = gatesS[lb][48 + u];
      c = c * fg + zg - ig;
      const float h = sigm(c) - og;
      hstageS[lb][u] = (f16)h;
      const int b = r * 16 + lb;
      if (layer == 1) out[((size_t)t * 32 + b) * 1024 + (n << 4) + u] = h;  // plain cached
    }
    __syncthreads();   // [C] hstageS -> wave 0

    if (w == 0) {
      if (active && lane < 32) {
        // coalesced h-store: 32 x 16B (2 per row)
        const int row = lane >> 1, half = lane & 1;
        f16x8 v = *(const f16x8*)&hstageS[row][half * 8];
        f16* hb = ((layer == 0) ? h1buf : h2buf) + (size_t)p_out * HN;
        st_coh_f16x8(hb + (size_t)(r * 16 + row) * 1024 + (n << 4) + half * 8, v);
      }
      asm volatile("s_waitcnt vmcnt(0)" ::: "memory");   // drain wave-0 h-stores
      if (tid == 0 && s < TSTEPS) st_coh_u32(bar + bid, us + 1u);
    }
    // other waves proceed; next iteration's gate [A] re-syncs the block
  }
}

__global__ void cvt_x_kernel(const float4* __restrict__ in, f16x4* __restrict__ outv, int n4) {
  int i = blockIdx.x * blockDim.x + threadIdx.x;
  const int stride = gridDim.x * blockDim.x;
  for (; i < n4; i += stride) {
    const float4 v = in[i];
    outv[i] = (f16x4){(f16)v.x, (f16)v.y, (f16)v.z, (f16)v.w};
  }
}

extern "C" void kernel_launch(void* const* d_in, const int* in_sizes, int n_in,
                              void* d_out, int out_size, void* d_ws, size_t ws_size,
                              hipStream_t stream) {
  const float* x    = (const float*)d_in[0];
  const float* wih0 = (const float*)d_in[1];
  const float* whh0 = (const float*)d_in[2];
  const float* b0   = (const float*)d_in[3];
  const float* wih1 = (const float*)d_in[4];
  const float* whh1 = (const float*)d_in[5];
  const float* b1   = (const float*)d_in[6];
  float* out = (float*)d_out;

  const size_t X16B   = (size_t)512 * 32 * 1024 * 2;  // fp16 copy of x (32MB)
  const size_t HBUFB  = (size_t)2 * HN * 2;           // 128KB per h (2 phases)
  const size_t STATEB = 2 * HBUFB + 16384;            // h1 + h2 + flags/gen copies

  char* ws = (char*)d_ws;
  const bool use_x16 = ws_size >= X16B + STATEB;
  const size_t soff = use_x16 ? X16B : 0;
  f16* x16        = (f16*)ws;
  f16* h1buf      = (f16*)(ws + soff);
  f16* h2buf      = (f16*)(ws + soff + HBUFB);
  unsigned* bar   = (unsigned*)(ws + soff + 2 * HBUFB);

  // zero h state + flags/gen (ws is poisoned; graph replays reuse it)
  (void)hipMemsetAsync(ws + soff, 0, STATEB, stream);

  if (use_x16) {
    const int n4 = 512 * 32 * 1024 / 4;
    cvt_x_kernel<<<2048, 256, 0, stream>>>((const float4*)x, (f16x4*)x16, n4);
    sublstm_persistent<1><<<NB, NT, 0, stream>>>(x, wih0, whh0, b0, wih1, whh1, b1,
                                                 x16, h1buf, h2buf, bar, out);
  } else {
    sublstm_persistent<0><<<NB, NT, 0, stream>>>(x, wih0, whh0, b0, wih1, whh1, b1,
                                                 x16, h1buf, h2buf, bar, out);
  }
}

// Round 22
// 2053.603 us; speedup vs baseline: 1.0886x; 1.0886x over previous
//
#include <hip/hip_runtime.h>
#include <hip/hip_fp16.h>
#include <stdint.h>

typedef _Float16 f16;
typedef _Float16 f16x8 __attribute__((ext_vector_type(8)));
typedef _Float16 f16x4 __attribute__((ext_vector_type(4)));
typedef float f32x4 __attribute__((ext_vector_type(4)));
typedef unsigned u32x4 __attribute__((ext_vector_type(4)));

#define TSTEPS 512
#define NB 256        // 2 layers x 64 colgroups x 2 rowgroups
#define NT 512        // 8 waves
#define HN (32 * 1024)

__device__ __forceinline__ float sigm(float v) { return 1.0f / (1.0f + __expf(-v)); }

// sc0 sc1 = device-coherent (write-through to memory-side L3 / L3-read).
__device__ __forceinline__ void ld_coh(f16x8& d, const f16* p) {
  asm volatile("global_load_dwordx4 %0, %1, off sc0 sc1" : "=v"(d) : "v"(p));
}
__device__ __forceinline__ void ld_plain(f16x8& d, const f16* p) {
  asm volatile("global_load_dwordx4 %0, %1, off" : "=v"(d) : "v"(p));
}
__device__ __forceinline__ void st_coh_f16x8(f16* p, f16x8 v) {
  asm volatile("global_store_dwordx4 %0, %1, off sc0 sc1" :: "v"(p), "v"(v) : "memory");
}
__device__ __forceinline__ void st_coh_u32(unsigned* p, unsigned v) {
  asm volatile("global_store_dword %0, %1, off sc0 sc1" :: "v"(p), "v"(v) : "memory");
}
__device__ __forceinline__ u32x4 ld_coh_u4(const unsigned* p) {
  u32x4 d;
  asm volatile("global_load_dwordx4 %0, %1, off sc0 sc1" : "=v"(d) : "v"(p));
  return d;
}
__device__ __forceinline__ unsigned ld_coh_u32(const unsigned* p) {
  unsigned d;
  asm volatile("global_load_dword %0, %1, off sc0 sc1" : "=v"(d) : "v"(p));
  return d;
}

// R20 kernel VERBATIM (best green: 2059us). R21's chain experiments (wave-1
// gate, gen x64 fan-out) both regressed and are reverted.
// Core: row-split (block = 16 rows x 64 cols), weights fully in registers,
// coalesced h exchange via per-wave LDS bounce with pipelined vmcnt drain,
// vectorized f32x4 reduce, slim barriers.
// Protocol (green lineage R2/R7/R8/R15/R19/R20): store-drain -> flag[bid] ->
// bid0-w0 scans 256 flags -> gen -> all gate on gen>=s. Rule #18 everywhere.
template<int USE_X16>
__global__ __launch_bounds__(NT, 2)
void sublstm_persistent(const float* __restrict__ x,
                        const float* __restrict__ wih0, const float* __restrict__ whh0,
                        const float* __restrict__ b0,
                        const float* __restrict__ wih1, const float* __restrict__ whh1,
                        const float* __restrict__ b1,
                        const f16* __restrict__ x16,
                        f16* __restrict__ h1buf, f16* __restrict__ h2buf,
                        unsigned* __restrict__ bar,   // [0..255] flags, [320] gen
                        float* __restrict__ out)
{
  __shared__ float red[8][16][68];   // 34.8KB per-wave partials
  __shared__ float gatesS[16][68];   //  4.4KB
  __shared__ float biasS[64];
  __shared__ f16 stage[8][4096];     // 64KB: per-wave private h-slice stage
  __shared__ f16 hstageS[16][16];    // 512B: h-output gather tile

  const int bid   = blockIdx.x;
  const int layer = bid >> 7;
  const int n     = (bid & 127) >> 1;   // colgroup 0..63
  const int r     = bid & 1;            // rowgroup 0..1
  const int tid   = threadIdx.x;
  const int lane  = tid & 63;
  const int w     = tid >> 6;
  const int c15   = lane & 15;
  const int g4    = lane >> 4;
  const int l5    = lane & 31;
  const int lh    = lane >> 5;
  unsigned* genp  = bar + 320;

  const float* wih = layer ? wih1 : wih0;
  const float* whh = layer ? whh1 : whh0;
  const float* bb  = layer ? b1   : b0;

  // one-time: 64-col weight slice -> registers (fp32 -> fp16), K-octant per wave
  const int kbase = w * 256 + g4 * 8;
  f16x8 breg[4][8];
  #pragma unroll
  for (int cc = 0; cc < 4; ++cc) {
    const int gate = cc * 1024 + (n << 4) + c15;
    const float* wr = (w < 4) ? (wih + (size_t)gate * 1024 + kbase)
                              : (whh + (size_t)gate * 1024 + (kbase - 1024));
    #pragma unroll
    for (int ks = 0; ks < 8; ++ks) {
      const float4 v0 = *(const float4*)(wr + ks * 32);
      const float4 v1 = *(const float4*)(wr + ks * 32 + 4);
      breg[cc][ks] = (f16x8){(f16)v0.x,(f16)v0.y,(f16)v0.z,(f16)v0.w,
                             (f16)v1.x,(f16)v1.y,(f16)v1.z,(f16)v1.w};
    }
  }
  if (tid < 64) biasS[tid] = bb[(tid >> 4) * 1024 + (n << 4) + (tid & 15)];
  __syncthreads();

  float c = 0.0f;        // cell state: thread tid<256 owns (lb = tid>>4, u = tid&15)
  f16x8 af[8];
  const int arow = r * 16 + c15;   // batch row for x frag loads

  for (int s = 0; s <= TSTEPS; ++s) {
    const int p_in  = s & 1;
    const int p_out = (s + 1) & 1;
    const bool active = (layer == 0) ? (s < TSTEPS) : (s >= 1);
    const int t = (layer == 0) ? s : (s - 1);
    const unsigned us = (unsigned)s;

    // x-issue early (plain cached, frag-order fine for cached path)
    if (active && layer == 0 && w < 4) {
      if (USE_X16) {
        const f16* bp = x16 + ((size_t)t * 32 + arow) * 1024 + kbase;
        #pragma unroll
        for (int ks = 0; ks < 8; ++ks) ld_plain(af[ks], bp + ks * 32);
      } else {
        const float* bp = x + ((size_t)t * 32 + arow) * 1024 + kbase;
        #pragma unroll
        for (int ks = 0; ks < 8; ++ks) {
          const float4 v0 = *(const float4*)(bp + ks * 32);
          const float4 v1 = *(const float4*)(bp + ks * 32 + 4);
          af[ks] = (f16x8){(f16)v0.x,(f16)v0.y,(f16)v0.z,(f16)v0.w,
                           (f16)v1.x,(f16)v1.y,(f16)v1.z,(f16)v1.w};
        }
      }
    }

    // centralized 2-hop gate (R15 verbatim): gen >= s    [A]
    if (s >= 1) {
      if (bid == 0 && w == 0) {
        while (true) {
          u32x4 d = ld_coh_u4(bar + (lane << 2));
          asm volatile("s_waitcnt vmcnt(0)" ::: "memory");
          __builtin_amdgcn_sched_barrier(0);
          if (__all(d.x >= us && d.y >= us && d.z >= us && d.w >= us)) break;
          __builtin_amdgcn_s_sleep(1);
        }
        if (lane == 0) st_coh_u32(genp, us);
      } else if (tid == 0) {
        while (true) {
          const unsigned gv = ld_coh_u32(genp);
          asm volatile("s_waitcnt vmcnt(0)" ::: "memory");
          __builtin_amdgcn_sched_barrier(0);
          if (gv >= us) break;
          __builtin_amdgcn_s_sleep(1);
        }
      }
      __syncthreads();
    }

    if (active) {
      if (!(layer == 0 && w < 4)) {
        // ---- coalesced h-slice load: 8 x 1KB contiguous instructions ----
        const f16* src; int kslice;
        if (layer == 0)   { src = h1buf + (size_t)p_in * HN; kslice = w * 256 - 1024; }
        else if (w < 4)   { src = h1buf + (size_t)p_in * HN; kslice = w * 256; }
        else              { src = h2buf + (size_t)p_in * HN; kslice = w * 256 - 1024; }
        #pragma unroll
        for (int i = 0; i < 8; ++i) {
          const int row = 2 * i + lh;                       // lanes 0-31: row 2i, 32-63: 2i+1
          ld_coh(af[i], src + (size_t)(r * 16 + row) * 1024 + kslice + l5 * 8);
        }
        // ---- pipelined stage: write each load as it retires (in-order) ----
        char* st = (char*)&stage[w][0];
#define DRAIN_WRITE(i, N)                                                        \
        asm volatile("s_waitcnt vmcnt(" N ")" ::: "memory");                     \
        { const int row_ = 2 * (i) + lh;                                         \
          const unsigned byte_ = ((unsigned)row_ << 9) |                         \
              ((((unsigned)l5 ^ ((unsigned)row_ & 7u)) << 4));                   \
          *(f16x8*)(st + byte_) = af[i]; }
        DRAIN_WRITE(0, "7")
        DRAIN_WRITE(1, "6")
        DRAIN_WRITE(2, "5")
        DRAIN_WRITE(3, "4")
        DRAIN_WRITE(4, "3")
        DRAIN_WRITE(5, "2")
        DRAIN_WRITE(6, "1")
        DRAIN_WRITE(7, "0")
#undef DRAIN_WRITE
        asm volatile("s_waitcnt lgkmcnt(0)" ::: "memory");
        __builtin_amdgcn_sched_barrier(0);
        // ---- fragment read from LDS (wave-private stage) ----
        #pragma unroll
        for (int ks = 0; ks < 8; ++ks) {
          const unsigned chunk = ((unsigned)(4 * ks + g4)) ^ ((unsigned)c15 & 7u);
          const unsigned byte = ((unsigned)c15 << 9) | (chunk << 4);
          af[ks] = *(const f16x8*)(st + byte);
        }
      }
      asm volatile("s_waitcnt vmcnt(0)" ::: "memory");
      __builtin_amdgcn_sched_barrier(0);

      f32x4 acc[4] = {{0,0,0,0},{0,0,0,0},{0,0,0,0},{0,0,0,0}};
      #pragma unroll
      for (int ks = 0; ks < 8; ++ks)
        #pragma unroll
        for (int cc = 0; cc < 4; ++cc)
          acc[cc] = __builtin_amdgcn_mfma_f32_16x16x32_f16(af[ks], breg[cc][ks], acc[cc], 0, 0, 0);

      // C frag: local row = g4*4 + rr, col = cc*16 + c15
      #pragma unroll
      for (int cc = 0; cc < 4; ++cc)
        #pragma unroll
        for (int rr = 0; rr < 4; ++rr)
          red[w][g4 * 4 + rr][cc * 16 + c15] = acc[cc][rr];
    }
    __syncthreads();   // [B] red complete across waves

    if (active && tid < 256) {
      // vectorized reduce: thread (lb, c4) sums 8 octant partials for 4 cols.
      // Same per-element order as scalar version -> bit-identical numerics.
      const int lb = tid >> 4;
      const int c4 = (tid & 15) << 2;
      f32x4 tot = *(const f32x4*)&biasS[c4];
      #pragma unroll
      for (int ww = 0; ww < 8; ++ww) tot += *(const f32x4*)&red[ww][lb][c4];
      f32x4 sg;
      #pragma unroll
      for (int j = 0; j < 4; ++j) sg[j] = sigm(tot[j]);
      *(f32x4*)&gatesS[lb][c4] = sg;
    }
    // no barrier: cell reader (lb,u)'s 4 source cols were written by threads
    // in the SAME 16-thread group (same wave); fence LDS program order.
    asm volatile("s_waitcnt lgkmcnt(0)" ::: "memory");

    if (active && tid < 256) {
      const int lb = tid >> 4, u = tid & 15;
      const float ig = gatesS[lb][u];
      const float og = gatesS[lb][16 + u];
      const float zg = gatesS[lb][32 + u];
      const float fg = gatesS[lb][48 + u];
      c = c * fg + zg - ig;
      const float h = sigm(c) - og;
      hstageS[lb][u] = (f16)h;
      const int b = r * 16 + lb;
      if (layer == 1) out[((size_t)t * 32 + b) * 1024 + (n << 4) + u] = h;  // plain cached
    }
    __syncthreads();   // [C] hstageS -> wave 0

    if (w == 0) {
      if (active && lane < 32) {
        // coalesced h-store: 32 x 16B (2 per row) instead of 256 x 2B
        const int row = lane >> 1, half = lane & 1;
        f16x8 v = *(const f16x8*)&hstageS[row][half * 8];
        f16* hb = ((layer == 0) ? h1buf : h2buf) + (size_t)p_out * HN;
        st_coh_f16x8(hb + (size_t)(r * 16 + row) * 1024 + (n << 4) + half * 8, v);
      }
      asm volatile("s_waitcnt vmcnt(0)" ::: "memory");   // drain wave-0 h-stores
      if (tid == 0 && s < TSTEPS) st_coh_u32(bar + bid, us + 1u);
    }
    // other waves proceed; next iteration's gate [A] re-syncs the block
  }
}

__global__ void cvt_x_kernel(const float4* __restrict__ in, f16x4* __restrict__ outv, int n4) {
  int i = blockIdx.x * blockDim.x + threadIdx.x;
  const int stride = gridDim.x * blockDim.x;
  for (; i < n4; i += stride) {
    const float4 v = in[i];
    outv[i] = (f16x4){(f16)v.x, (f16)v.y, (f16)v.z, (f16)v.w};
  }
}

extern "C" void kernel_launch(void* const* d_in, const int* in_sizes, int n_in,
                              void* d_out, int out_size, void* d_ws, size_t ws_size,
                              hipStream_t stream) {
  const float* x    = (const float*)d_in[0];
  const float* wih0 = (const float*)d_in[1];
  const float* whh0 = (const float*)d_in[2];
  const float* b0   = (const float*)d_in[3];
  const float* wih1 = (const float*)d_in[4];
  const float* whh1 = (const float*)d_in[5];
  const float* b1   = (const float*)d_in[6];
  float* out = (float*)d_out;

  const size_t X16B   = (size_t)512 * 32 * 1024 * 2;  // fp16 copy of x (32MB)
  const size_t HBUFB  = (size_t)2 * HN * 2;           // 128KB per h (2 phases)
  const size_t STATEB = 2 * HBUFB + 4096;             // h1 + h2 + flags/gen

  char* ws = (char*)d_ws;
  const bool use_x16 = ws_size >= X16B + STATEB;
  const size_t soff = use_x16 ? X16B : 0;
  f16* x16        = (f16*)ws;
  f16* h1buf      = (f16*)(ws + soff);
  f16* h2buf      = (f16*)(ws + soff + HBUFB);
  unsigned* bar   = (unsigned*)(ws + soff + 2 * HBUFB);

  // zero h state + flags/gen (ws is poisoned; graph replays reuse it)
  (void)hipMemsetAsync(ws + soff, 0, STATEB, stream);

  if (use_x16) {
    const int n4 = 512 * 32 * 1024 / 4;
    cvt_x_kernel<<<2048, 256, 0, stream>>>((const float4*)x, (f16x4*)x16, n4);
    sublstm_persistent<1><<<NB, NT, 0, stream>>>(x, wih0, whh0, b0, wih1, whh1, b1,
                                                 x16, h1buf, h2buf, bar, out);
  } else {
    sublstm_persistent<0><<<NB, NT, 0, stream>>>(x, wih0, whh0, b0, wih1, whh1, b1,
                                                 x16, h1buf, h2buf, bar, out);
  }
}